// Round 1
// baseline (571.557 us; speedup 1.0000x reference)
//
#include <hip/hip_runtime.h>

#define LEAF_SZ 32
#define MAXN 16384
#define MAXNODES 32768
#define MAXG 64
#define QCAP 2048

// Static device scratch (avoids assumptions about ws_size; fully rewritten each call).
__device__ int   g_perm[MAXN];
__device__ int   g_inv[MAXN];
__device__ int   g_ptmp[MAXN];
__device__ float g_px[MAXN];
__device__ float g_py[MAXN];
__device__ float g_pz[MAXN];
__device__ float g_ps[MAXN];
__device__ int   g_nstart[MAXNODES];
__device__ int   g_nend[MAXNODES];
__device__ int   g_nfirst[MAXNODES];
__device__ int   g_nnum[MAXNODES];
__device__ float g_ncx[MAXNODES];
__device__ float g_ncy[MAXNODES];
__device__ float g_ncz[MAXNODES];
__device__ float g_nhalf[MAXNODES];
__device__ float g_nmx[MAXNODES];
__device__ float g_nmy[MAXNODES];
__device__ float g_nmz[MAXNODES];
__device__ float g_nQ[MAXNODES];
__device__ int   g_root[MAXG];

// ---------------------------------------------------------------------------
// Level-synchronous octree build, one block, one wave per node per level.
// Exactly mirrors the reference _build_tree: bbox-center split, key=(p>=c),
// leaf when count<=32 OR <=1 nonempty octant bin.
// ---------------------------------------------------------------------------
__global__ __launch_bounds__(1024)
void build_kernel(const float* __restrict__ pos, const int* __restrict__ batch,
                  const float* __restrict__ src, int N, int n_graphs)
{
    __shared__ int s_gfirst[MAXG];
    __shared__ int s_gend[MAXG];
    __shared__ int s_ncount, s_lb, s_le;
    __shared__ int s_cursor[16][8];

    const int tid  = threadIdx.x;
    const int wid  = tid >> 6;
    const int lane = tid & 63;
    const int NW   = blockDim.x >> 6;

    for (int g = tid; g < n_graphs && g < MAXG; g += blockDim.x) { s_gfirst[g] = -1; s_gend[g] = 0; }
    __syncthreads();
    // batch is sorted -> graphs are contiguous ranges
    for (int i = tid; i < N; i += blockDim.x) {
        g_perm[i] = i;
        int b = batch[i];
        if (i == 0     || batch[i-1] != b) s_gfirst[b] = i;
        if (i == N - 1 || batch[i+1] != b) s_gend[b]   = i + 1;
    }
    __syncthreads();
    if (tid == 0) {
        int nc = 0;
        for (int g = 0; g < n_graphs && g < MAXG; ++g) {
            if (s_gfirst[g] >= 0) {
                g_root[g]    = nc;
                g_nstart[nc] = s_gfirst[g];
                g_nend[nc]   = s_gend[g];
                ++nc;
            } else {
                g_root[g] = -1;
            }
        }
        s_ncount = nc; s_lb = 0; s_le = nc;
    }

    while (true) {
        __syncthreads();
        const int lb = s_lb, le = s_le;
        if (lb >= le) break;                       // uniform exit

        for (int n = lb + wid; n < le; n += NW) {  // wave-per-node
            const int st = g_nstart[n], en = g_nend[n];
            const int cnt = en - st;

            // pass 1: bbox + mean-center + total charge
            float mnx = 3.402823466e38f, mny = mnx, mnz = mnx;
            float mxx = -mnx, mxy = -mnx, mxz = -mnx;
            double sx = 0.0, sy = 0.0, sz = 0.0, sq = 0.0;
            for (int j = st + lane; j < en; j += 64) {
                int a = g_perm[j];
                float px = pos[3*a], py = pos[3*a+1], pz = pos[3*a+2];
                mnx = fminf(mnx, px); mny = fminf(mny, py); mnz = fminf(mnz, pz);
                mxx = fmaxf(mxx, px); mxy = fmaxf(mxy, py); mxz = fmaxf(mxz, pz);
                sx += (double)px; sy += (double)py; sz += (double)pz; sq += (double)src[a];
            }
            for (int o = 1; o < 64; o <<= 1) {
                mnx = fminf(mnx, __shfl_xor(mnx, o));
                mny = fminf(mny, __shfl_xor(mny, o));
                mnz = fminf(mnz, __shfl_xor(mnz, o));
                mxx = fmaxf(mxx, __shfl_xor(mxx, o));
                mxy = fmaxf(mxy, __shfl_xor(mxy, o));
                mxz = fmaxf(mxz, __shfl_xor(mxz, o));
                sx += __shfl_xor(sx, o);
                sy += __shfl_xor(sy, o);
                sz += __shfl_xor(sz, o);
                sq += __shfl_xor(sq, o);
            }
            const float cx = 0.5f * (mnx + mxx);
            const float cy = 0.5f * (mny + mxy);
            const float cz = 0.5f * (mnz + mxz);
            const float half = 0.5f * fmaxf(fmaxf(mxx - mnx, mxy - mny), mxz - mnz);
            if (lane == 0) {
                g_ncx[n] = cx; g_ncy[n] = cy; g_ncz[n] = cz; g_nhalf[n] = half;
                const float fc = (float)cnt;
                g_nmx[n] = (float)sx / fc;
                g_nmy[n] = (float)sy / fc;
                g_nmz[n] = (float)sz / fc;
                g_nQ[n]  = (float)sq;
            }
            if (cnt <= LEAF_SZ) { if (lane == 0) g_nnum[n] = 0; continue; }

            // pass 2: octant counts
            int c8[8] = {0,0,0,0,0,0,0,0};
            for (int j = st + lane; j < en; j += 64) {
                int a = g_perm[j];
                int oct = (pos[3*a] >= cx ? 1 : 0) | (pos[3*a+1] >= cy ? 2 : 0) | (pos[3*a+2] >= cz ? 4 : 0);
                c8[oct]++;
            }
            #pragma unroll
            for (int k = 0; k < 8; ++k)
                for (int o = 1; o < 64; o <<= 1)
                    c8[k] += __shfl_xor(c8[k], o);
            int nonempty = 0;
            #pragma unroll
            for (int k = 0; k < 8; ++k) nonempty += (c8[k] > 0) ? 1 : 0;
            if (nonempty <= 1) { if (lane == 0) g_nnum[n] = 0; continue; } // degenerate -> leaf

            int base = 0;
            if (lane == 0) base = atomicAdd(&s_ncount, nonempty);
            base = __shfl(base, 0);

            int acc = st, cidx = base;
            int off[8];
            #pragma unroll
            for (int k = 0; k < 8; ++k) {
                off[k] = acc;
                if (c8[k] > 0) {
                    if (lane == 0) { g_nstart[cidx] = acc; g_nend[cidx] = acc + c8[k]; }
                    ++cidx;
                }
                acc += c8[k];
            }
            if (lane == 0) { g_nfirst[n] = base; g_nnum[n] = nonempty; }

            // pass 3: scatter segment into child order
            if (lane < 8) s_cursor[wid][lane] = off[lane];
            __builtin_amdgcn_wave_barrier();
            for (int j = st + lane; j < en; j += 64) {
                int a = g_perm[j];
                int oct = (pos[3*a] >= cx ? 1 : 0) | (pos[3*a+1] >= cy ? 2 : 0) | (pos[3*a+2] >= cz ? 4 : 0);
                int p = atomicAdd(&s_cursor[wid][oct], 1);
                g_ptmp[p] = a;
            }
            __builtin_amdgcn_wave_barrier();
            __threadfence_block();   // drain scatter stores before re-reading
            for (int j = st + lane; j < en; j += 64) g_perm[j] = g_ptmp[j];
        }
        __syncthreads();
        if (tid == 0) { s_lb = le; s_le = s_ncount; }
    }

    __syncthreads();
    // inverse permutation + perm-ordered gathers for coalesced leaf sums
    for (int i = tid; i < N; i += blockDim.x) {
        int a = g_perm[i];
        g_inv[a] = i;
        g_px[i] = pos[3*a];
        g_py[i] = pos[3*a+1];
        g_pz[i] = pos[3*a+2];
        g_ps[i] = src[a];
    }
}

// ---------------------------------------------------------------------------
// One wave per target: wave-parallel BFS with LDS ring queue. Each lane pops
// a node; MAC accept -> monopole term, leaf -> direct sum, else push children.
// ---------------------------------------------------------------------------
__global__ __launch_bounds__(256)
void traverse_kernel(const float* __restrict__ pos, const int* __restrict__ batch,
                     const float* __restrict__ src, const float* __restrict__ p_scr,
                     const float* __restrict__ p_soft, float* __restrict__ out, int N)
{
    __shared__ int s_q[4][QCAP];
    __shared__ int s_qt[4];
    const int wid  = threadIdx.x >> 6;
    const int lane = threadIdx.x & 63;
    const int slot = blockIdx.x * 4 + wid;
    if (slot >= N) return;                 // wave-uniform; no __syncthreads used
    const int t = g_perm[slot];            // perm order -> co-resident waves share tree regions

    const float scr   = p_scr[0];
    const float soft  = p_soft[0];
    const float soft2 = soft * soft;
    const float tx = pos[3*t], ty = pos[3*t+1], tz = pos[3*t+2];
    const int inv_t = slot;                // g_inv[t] == slot by construction

    volatile int* q = s_q[wid];
    if (lane == 0) { q[0] = g_root[batch[t]]; s_qt[wid] = 1; }
    __builtin_amdgcn_wave_barrier();

    double phi = 0.0;
    int qh = 0;
    while (true) {
        __builtin_amdgcn_wave_barrier();
        int qt = ((volatile int*)s_qt)[wid];
        if (qh >= qt) break;
        int take = qt - qh; if (take > 64) take = 64;
        int node = (lane < take) ? q[(qh + lane) & (QCAP - 1)] : -1;
        qh += take;
        if (node >= 0) {
            const int st = g_nstart[node], en = g_nend[node];
            const int nc = g_nnum[node];
            if (nc == 0) {
                // leaf (or degenerate): direct near-field sum, skip self
                for (int j = st; j < en; ++j) {
                    if (j == inv_t) continue;
                    float dx = tx - g_px[j];
                    float dy = ty - g_py[j];
                    float dz = tz - g_pz[j];
                    float r = sqrtf(dx*dx + dy*dy + dz*dz + soft2);
                    phi += (double)(g_ps[j] * expf(-scr * r) / r);
                }
            } else {
                float dx = tx - g_ncx[node];
                float dy = ty - g_ncy[node];
                float dz = tz - g_ncz[node];
                float dist = sqrtf(dx*dx + dy*dy + dz*dz + soft2);
                float diam = fmaxf(2.0f * g_nhalf[node], 1e-9f);
                bool inside = (inv_t >= st) && (inv_t < en);
                // diam/dist < 0.5 (fp64 in ref) == diam < 0.5f*dist (0.5x is exact)
                if (!inside && diam < 0.5f * dist) {
                    float mx = tx - g_nmx[node];
                    float my = ty - g_nmy[node];
                    float mz = tz - g_nmz[node];
                    float r = sqrtf(mx*mx + my*my + mz*mz + soft2);
                    phi += (double)(g_nQ[node] * expf(-scr * r) / r);
                } else {
                    int p = atomicAdd(&s_qt[wid], nc);
                    int fc = g_nfirst[node];
                    for (int c = 0; c < nc; ++c) q[(p + c) & (QCAP - 1)] = fc + c;
                }
            }
        }
    }

    #pragma unroll
    for (int o = 1; o < 64; o <<= 1) phi += __shfl_xor(phi, o);
    if (lane == 0) out[t] = 0.5f * (src[t] * (float)phi);
}

extern "C" void kernel_launch(void* const* d_in, const int* in_sizes, int n_in,
                              void* d_out, int out_size, void* d_ws, size_t ws_size,
                              hipStream_t stream) {
    const float* pos    = (const float*)d_in[0];
    const int*   batch  = (const int*)  d_in[1];
    // d_in[2] = cell (zeros, unused by open-boundary path)
    const float* source = (const float*)d_in[3];
    const float* p_scr  = (const float*)d_in[4];
    const float* p_soft = (const float*)d_in[5];

    const int N        = in_sizes[0] / 3;
    const int n_graphs = in_sizes[2] / 9;

    build_kernel<<<1, 1024, 0, stream>>>(pos, batch, source, N, n_graphs);

    const int blocks = (N + 3) / 4;  // 4 waves (targets) per 256-thread block
    traverse_kernel<<<blocks, 256, 0, stream>>>(pos, batch, source, p_scr, p_soft,
                                                (float*)d_out, N);
}

// Round 2
// 341.942 us; speedup vs baseline: 1.6715x; 1.6715x over previous
//
#include <hip/hip_runtime.h>

#define LEAF_SZ 32
#define MAXN 16384
#define MAXNODES 32768
#define MAXG 64
#define QCAP 2048
#define MAXLEV 12
#define LGRID 128

// Static device scratch (fully rewritten each call; no cross-call state relied on).
__device__ int   g_perm[MAXN];
__device__ float g_px[MAXN];
__device__ float g_py[MAXN];
__device__ float g_pz[MAXN];
__device__ float g_ps[MAXN];
__device__ int   g_ptmp[MAXN];
__device__ float g_xtmp[MAXN];
__device__ float g_ytmp[MAXN];
__device__ float g_ztmp[MAXN];
__device__ float g_stmp[MAXN];
__device__ int   g_nstart[MAXNODES];
__device__ int   g_nend[MAXNODES];
__device__ int   g_nfirst[MAXNODES];
__device__ int   g_nnum[MAXNODES];
__device__ float g_ncx[MAXNODES];
__device__ float g_ncy[MAXNODES];
__device__ float g_ncz[MAXNODES];
__device__ float g_nhalf[MAXNODES];
__device__ float g_nmx[MAXNODES];
__device__ float g_nmy[MAXNODES];
__device__ float g_nmz[MAXNODES];
__device__ float g_nQ[MAXNODES];
__device__ int   g_root[MAXG];
__device__ int   g_ncount;
__device__ int   g_lrange[MAXLEV + 2];
__device__ int   g_done[MAXLEV];

struct NodeSh {
    float  mn[4][3], mx[4][3];
    double sx[4], sy[4], sz[4], sq[4];
    int    c8[4][8];
    int    cur[8];
    float  cc[3];
    int    info;   // -1 leaf/degenerate (stop), 1 split
};

// Block-cooperative (256 threads) processing of one node: bbox+monopole,
// octant split at bbox center (>= rule), leaf if cnt<=32 or <=1 nonempty bin.
// Points/charges are kept gathered in perm order -> all loads coalesced.
__device__ __forceinline__ void process_node(NodeSh& sh, int n)
{
    const int tid  = threadIdx.x;
    const int wid  = tid >> 6;
    const int lane = tid & 63;
    const int st = g_nstart[n], en = g_nend[n];
    const int cnt = en - st;

    // pass 1: bbox + mean-center + total charge
    float mnx = 3.402823466e38f, mny = mnx, mnz = mnx;
    float mxx = -mnx, mxy = -mnx, mxz = -mnx;
    double sx = 0.0, sy = 0.0, sz = 0.0, sq = 0.0;
    for (int j = st + tid; j < en; j += 256) {
        float x = g_px[j], y = g_py[j], z = g_pz[j], s = g_ps[j];
        mnx = fminf(mnx, x); mny = fminf(mny, y); mnz = fminf(mnz, z);
        mxx = fmaxf(mxx, x); mxy = fmaxf(mxy, y); mxz = fmaxf(mxz, z);
        sx += (double)x; sy += (double)y; sz += (double)z; sq += (double)s;
    }
    for (int o = 1; o < 64; o <<= 1) {
        mnx = fminf(mnx, __shfl_xor(mnx, o));
        mny = fminf(mny, __shfl_xor(mny, o));
        mnz = fminf(mnz, __shfl_xor(mnz, o));
        mxx = fmaxf(mxx, __shfl_xor(mxx, o));
        mxy = fmaxf(mxy, __shfl_xor(mxy, o));
        mxz = fmaxf(mxz, __shfl_xor(mxz, o));
        sx += __shfl_xor(sx, o);
        sy += __shfl_xor(sy, o);
        sz += __shfl_xor(sz, o);
        sq += __shfl_xor(sq, o);
    }
    if (lane == 0) {
        sh.mn[wid][0] = mnx; sh.mn[wid][1] = mny; sh.mn[wid][2] = mnz;
        sh.mx[wid][0] = mxx; sh.mx[wid][1] = mxy; sh.mx[wid][2] = mxz;
        sh.sx[wid] = sx; sh.sy[wid] = sy; sh.sz[wid] = sz; sh.sq[wid] = sq;
    }
    __syncthreads();
    if (tid == 0) {
        float a0 = sh.mn[0][0], a1 = sh.mn[0][1], a2 = sh.mn[0][2];
        float b0 = sh.mx[0][0], b1 = sh.mx[0][1], b2 = sh.mx[0][2];
        double tx = sh.sx[0], ty = sh.sy[0], tz = sh.sz[0], tq = sh.sq[0];
        for (int w = 1; w < 4; ++w) {
            a0 = fminf(a0, sh.mn[w][0]); a1 = fminf(a1, sh.mn[w][1]); a2 = fminf(a2, sh.mn[w][2]);
            b0 = fmaxf(b0, sh.mx[w][0]); b1 = fmaxf(b1, sh.mx[w][1]); b2 = fmaxf(b2, sh.mx[w][2]);
            tx += sh.sx[w]; ty += sh.sy[w]; tz += sh.sz[w]; tq += sh.sq[w];
        }
        float cx = 0.5f * (a0 + b0), cy = 0.5f * (a1 + b1), cz = 0.5f * (a2 + b2);
        g_ncx[n] = cx; g_ncy[n] = cy; g_ncz[n] = cz;
        g_nhalf[n] = 0.5f * fmaxf(fmaxf(b0 - a0, b1 - a1), b2 - a2);
        const float fc = (float)cnt;
        g_nmx[n] = (float)tx / fc; g_nmy[n] = (float)ty / fc; g_nmz[n] = (float)tz / fc;
        g_nQ[n]  = (float)tq;
        sh.cc[0] = cx; sh.cc[1] = cy; sh.cc[2] = cz;
        if (cnt <= LEAF_SZ) { g_nnum[n] = 0; sh.info = -1; } else sh.info = 0;
    }
    __syncthreads();
    if (sh.info < 0) return;
    const float cx = sh.cc[0], cy = sh.cc[1], cz = sh.cc[2];

    // pass 2: octant counts
    int c8[8] = {0,0,0,0,0,0,0,0};
    for (int j = st + tid; j < en; j += 256) {
        int oct = (g_px[j] >= cx ? 1 : 0) | (g_py[j] >= cy ? 2 : 0) | (g_pz[j] >= cz ? 4 : 0);
        c8[oct]++;
    }
    #pragma unroll
    for (int k = 0; k < 8; ++k)
        for (int o = 1; o < 64; o <<= 1)
            c8[k] += __shfl_xor(c8[k], o);
    if (lane == 0)
        #pragma unroll
        for (int k = 0; k < 8; ++k) sh.c8[wid][k] = c8[k];
    __syncthreads();
    if (tid == 0) {
        int tot[8], nonempty = 0;
        #pragma unroll
        for (int k = 0; k < 8; ++k) {
            tot[k] = sh.c8[0][k] + sh.c8[1][k] + sh.c8[2][k] + sh.c8[3][k];
            nonempty += (tot[k] > 0) ? 1 : 0;
        }
        if (nonempty <= 1) { g_nnum[n] = 0; sh.info = -1; }
        else {
            int base = atomicAdd(&g_ncount, nonempty);
            int acc = st, ci = base;
            #pragma unroll
            for (int k = 0; k < 8; ++k) {
                sh.cur[k] = acc;
                if (tot[k] > 0) { g_nstart[ci] = acc; g_nend[ci] = acc + tot[k]; ++ci; }
                acc += tot[k];
            }
            g_nfirst[n] = base; g_nnum[n] = nonempty;
            sh.info = 1;
        }
    }
    __syncthreads();
    if (sh.info < 0) return;

    // pass 3: scatter into child order (ids + gathered pos/charge together)
    for (int j = st + tid; j < en; j += 256) {
        float x = g_px[j], y = g_py[j], z = g_pz[j], s = g_ps[j];
        int id = g_perm[j];
        int oct = (x >= cx ? 1 : 0) | (y >= cy ? 2 : 0) | (z >= cz ? 4 : 0);
        int p = atomicAdd(&sh.cur[oct], 1);
        g_ptmp[p] = id; g_xtmp[p] = x; g_ytmp[p] = y; g_ztmp[p] = z; g_stmp[p] = s;
    }
    __syncthreads();
    for (int j = st + tid; j < en; j += 256) {
        g_perm[j] = g_ptmp[j];
        g_px[j] = g_xtmp[j]; g_py[j] = g_ytmp[j]; g_pz[j] = g_ztmp[j]; g_ps[j] = g_stmp[j];
    }
}

__global__ void initA_kernel(const float* __restrict__ pos, const float* __restrict__ src, int N)
{
    int i = blockIdx.x * blockDim.x + threadIdx.x;
    if (i < N) {
        g_perm[i] = i;
        g_px[i] = pos[3*i]; g_py[i] = pos[3*i+1]; g_pz[i] = pos[3*i+2];
        g_ps[i] = src[i];
    }
}

__global__ __launch_bounds__(256) void initB_kernel(const int* __restrict__ batch, int N, int n_graphs)
{
    __shared__ int s_first[MAXG], s_end[MAXG];
    const int tid = threadIdx.x;
    for (int g = tid; g < MAXG; g += 256) { s_first[g] = -1; s_end[g] = 0; }
    __syncthreads();
    for (int i = tid; i < N; i += 256) {
        int b = batch[i];
        if (i == 0     || batch[i-1] != b) s_first[b] = i;
        if (i == N - 1 || batch[i+1] != b) s_end[b]   = i + 1;
    }
    __syncthreads();
    if (tid == 0) {
        int nc = 0;
        for (int g = 0; g < n_graphs && g < MAXG; ++g) {
            if (s_first[g] >= 0) {
                g_root[g] = nc;
                g_nstart[nc] = s_first[g];
                g_nend[nc]   = s_end[g];
                ++nc;
            } else g_root[g] = -1;
        }
        g_ncount = nc; g_lrange[0] = 0; g_lrange[1] = nc;
        for (int l = 0; l < MAXLEV; ++l) g_done[l] = 0;
    }
}

// One launch per level; kernel boundary = device-wide barrier (graph-safe).
__global__ __launch_bounds__(256) void level_kernel(int lev)
{
    __shared__ NodeSh sh;
    const int lb = g_lrange[lev], le = g_lrange[lev + 1];
    for (int n = lb + blockIdx.x; n < le; n += gridDim.x) {
        __syncthreads();
        process_node(sh, n);
    }
    __syncthreads();
    if (threadIdx.x == 0) {
        __threadfence();
        int d = atomicAdd(&g_done[lev], 1);
        if (d == (int)gridDim.x - 1)
            g_lrange[lev + 2] = atomicAdd(&g_ncount, 0);   // publish next level range
    }
}

// Safety net: completes any levels beyond MAXLEV (normally zero work).
__global__ __launch_bounds__(256) void finish_kernel()
{
    __shared__ NodeSh sh;
    __shared__ int s_le;
    int lb = g_lrange[MAXLEV], le = g_lrange[MAXLEV + 1];
    while (lb < le) {
        for (int n = lb; n < le; ++n) {
            __syncthreads();
            process_node(sh, n);
        }
        __syncthreads();
        if (threadIdx.x == 0) s_le = atomicAdd(&g_ncount, 0);
        __syncthreads();
        lb = le; le = s_le;
    }
}

// ---------------------------------------------------------------------------
// One wave per target: wave-parallel BFS with LDS ring queue.
// ---------------------------------------------------------------------------
__global__ __launch_bounds__(256)
void traverse_kernel(const int* __restrict__ batch,
                     const float* __restrict__ p_scr, const float* __restrict__ p_soft,
                     float* __restrict__ out, int N)
{
    __shared__ int s_q[4][QCAP];
    __shared__ int s_qt[4];
    const int wid  = threadIdx.x >> 6;
    const int lane = threadIdx.x & 63;
    const int slot = blockIdx.x * 4 + wid;
    if (slot >= N) return;                 // wave-uniform; no __syncthreads used
    const int t = g_perm[slot];            // perm order -> co-resident waves share tree regions

    const float scr   = p_scr[0];
    const float soft  = p_soft[0];
    const float soft2 = soft * soft;
    const float tx = g_px[slot], ty = g_py[slot], tz = g_pz[slot];
    const int inv_t = slot;

    volatile int* q = s_q[wid];
    if (lane == 0) { q[0] = g_root[batch[t]]; s_qt[wid] = 1; }
    __builtin_amdgcn_wave_barrier();

    double phi = 0.0;
    int qh = 0;
    while (true) {
        __builtin_amdgcn_wave_barrier();
        int qt = ((volatile int*)s_qt)[wid];
        if (qh >= qt) break;
        int take = qt - qh; if (take > 64) take = 64;
        int node = (lane < take) ? q[(qh + lane) & (QCAP - 1)] : -1;
        qh += take;
        if (node >= 0) {
            const int st = g_nstart[node], en = g_nend[node];
            const int nc = g_nnum[node];
            if (nc == 0) {
                for (int j = st; j < en; ++j) {
                    if (j == inv_t) continue;
                    float dx = tx - g_px[j];
                    float dy = ty - g_py[j];
                    float dz = tz - g_pz[j];
                    float r = sqrtf(dx*dx + dy*dy + dz*dz + soft2);
                    phi += (double)(g_ps[j] * expf(-scr * r) / r);
                }
            } else {
                float dx = tx - g_ncx[node];
                float dy = ty - g_ncy[node];
                float dz = tz - g_ncz[node];
                float dist = sqrtf(dx*dx + dy*dy + dz*dz + soft2);
                float diam = fmaxf(2.0f * g_nhalf[node], 1e-9f);
                bool inside = (inv_t >= st) && (inv_t < en);
                if (!inside && diam < 0.5f * dist) {
                    float mx = tx - g_nmx[node];
                    float my = ty - g_nmy[node];
                    float mz = tz - g_nmz[node];
                    float r = sqrtf(mx*mx + my*my + mz*mz + soft2);
                    phi += (double)(g_nQ[node] * expf(-scr * r) / r);
                } else {
                    int p = atomicAdd(&s_qt[wid], nc);
                    int fc = g_nfirst[node];
                    for (int c = 0; c < nc; ++c) q[(p + c) & (QCAP - 1)] = fc + c;
                }
            }
        }
    }

    #pragma unroll
    for (int o = 1; o < 64; o <<= 1) phi += __shfl_xor(phi, o);
    if (lane == 0) out[t] = 0.5f * (g_ps[slot] * (float)phi);
}

extern "C" void kernel_launch(void* const* d_in, const int* in_sizes, int n_in,
                              void* d_out, int out_size, void* d_ws, size_t ws_size,
                              hipStream_t stream) {
    const float* pos    = (const float*)d_in[0];
    const int*   batch  = (const int*)  d_in[1];
    const float* source = (const float*)d_in[3];
    const float* p_scr  = (const float*)d_in[4];
    const float* p_soft = (const float*)d_in[5];

    const int N        = in_sizes[0] / 3;
    const int n_graphs = in_sizes[2] / 9;

    initA_kernel<<<(N + 255) / 256, 256, 0, stream>>>(pos, source, N);
    initB_kernel<<<1, 256, 0, stream>>>(batch, N, n_graphs);
    for (int lev = 0; lev < MAXLEV; ++lev)
        level_kernel<<<LGRID, 256, 0, stream>>>(lev);
    finish_kernel<<<1, 256, 0, stream>>>();

    const int blocks = (N + 3) / 4;  // 4 waves (targets) per 256-thread block
    traverse_kernel<<<blocks, 256, 0, stream>>>(batch, p_scr, p_soft, (float*)d_out, N);
}

// Round 3
// 314.231 us; speedup vs baseline: 1.8189x; 1.0882x over previous
//
#include <hip/hip_runtime.h>

#define LEAF_SZ 32
#define MAXN 16384
#define MAXNODES 32768
#define MAXG 64
#define NQ 1024
#define PCAP 1024
#define BGRID 128

// Static device scratch (fully rewritten each call; no cross-call state relied on).
__device__ int    g_perm[MAXN];
__device__ int    g_ptmp[MAXN];
__device__ float4 g_p4[MAXN];    // x,y,z,charge in perm order
__device__ float4 g_t4[MAXN];
__device__ int    g_nstart[MAXNODES];
__device__ int    g_nend[MAXNODES];
__device__ int4   g_nmeta[MAXNODES];  // st, en, first_child, n_children(0=leaf)
__device__ float4 g_nc4[MAXNODES];    // bbox center + half (MAC)
__device__ float4 g_nm4[MAXNODES];    // mean center + total charge (monopole)
__device__ int    g_ready[MAXNODES];
__device__ int    g_root[MAXG];
__device__ int    g_ncount;
__device__ int    g_claim;
__device__ int    g_finished;

__global__ void initA_kernel(const float* __restrict__ pos, const float* __restrict__ src, int N)
{
    int i = blockIdx.x * blockDim.x + threadIdx.x;
    if (i < MAXNODES) g_ready[i] = 0;
    if (i < N) {
        g_perm[i] = i;
        g_p4[i] = make_float4(pos[3*i], pos[3*i+1], pos[3*i+2], src[i]);
    }
}

__global__ __launch_bounds__(256) void initB_kernel(const int* __restrict__ batch, int N, int n_graphs)
{
    __shared__ int s_first[MAXG], s_end[MAXG];
    const int tid = threadIdx.x;
    for (int g = tid; g < MAXG; g += 256) { s_first[g] = -1; s_end[g] = 0; }
    __syncthreads();
    for (int i = tid; i < N; i += 256) {
        int b = batch[i];
        if (i == 0     || batch[i-1] != b) s_first[b] = i;
        if (i == N - 1 || batch[i+1] != b) s_end[b]   = i + 1;
    }
    __syncthreads();
    if (tid == 0) {
        int nc = 0;
        for (int g = 0; g < n_graphs && g < MAXG; ++g) {
            if (s_first[g] >= 0) {
                g_root[g] = nc;
                g_nstart[nc] = s_first[g];
                g_nend[nc]   = s_end[g];
                g_ready[nc]  = 1;
                ++nc;
            } else g_root[g] = -1;
        }
        g_ncount = nc; g_claim = 0; g_finished = 0;
    }
}

// ---------------------------------------------------------------------------
// Persistent work-queue build: blocks claim node indices; per-node ready flag
// gates dependency (parent scatter done -> children ready). Done when
// finished == allocated (finished read FIRST makes the check race-free).
// 128 blocks << 256 CUs -> all co-resident; spin-wait is safe.
// ---------------------------------------------------------------------------
__global__ __launch_bounds__(256) void build_kernel()
{
    __shared__ float  s_mn[4][3], s_mx[4][3];
    __shared__ double s_sx[4], s_sy[4], s_sz[4], s_sq[4];
    __shared__ int    s_c8[4][8];
    __shared__ int    s_cur[8];
    __shared__ float  s_cc[3];
    __shared__ int    s_info, s_node, s_base, s_num;

    const int tid  = threadIdx.x;
    const int wid  = tid >> 6;
    const int lane = tid & 63;

    while (true) {
        if (tid == 0) {
            int i = atomicAdd(&g_claim, 1);
            int nd;
            while (true) {
                int fin = atomicAdd(&g_finished, 0);   // read finished FIRST
                int cnt = atomicAdd(&g_ncount, 0);
                if (i < cnt) {
                    if (atomicAdd(&g_ready[i], 0)) { nd = i; break; }
                } else if (fin == cnt) { nd = -1; break; }
                __builtin_amdgcn_s_sleep(1);
            }
            s_node = nd;
        }
        __syncthreads();
        const int n = s_node;
        if (n < 0) break;
        __threadfence();                 // acquire: see parent's scattered data
        const int st = g_nstart[n], en = g_nend[n];
        const int cnt = en - st;

        // pass 1: bbox + mean-center + total charge
        float mnx = 3.402823466e38f, mny = mnx, mnz = mnx;
        float mxx = -mnx, mxy = -mnx, mxz = -mnx;
        double sx = 0.0, sy = 0.0, sz = 0.0, sq = 0.0;
        for (int j = st + tid; j < en; j += 256) {
            float4 p = g_p4[j];
            mnx = fminf(mnx, p.x); mny = fminf(mny, p.y); mnz = fminf(mnz, p.z);
            mxx = fmaxf(mxx, p.x); mxy = fmaxf(mxy, p.y); mxz = fmaxf(mxz, p.z);
            sx += (double)p.x; sy += (double)p.y; sz += (double)p.z; sq += (double)p.w;
        }
        for (int o = 1; o < 64; o <<= 1) {
            mnx = fminf(mnx, __shfl_xor(mnx, o));
            mny = fminf(mny, __shfl_xor(mny, o));
            mnz = fminf(mnz, __shfl_xor(mnz, o));
            mxx = fmaxf(mxx, __shfl_xor(mxx, o));
            mxy = fmaxf(mxy, __shfl_xor(mxy, o));
            mxz = fmaxf(mxz, __shfl_xor(mxz, o));
            sx += __shfl_xor(sx, o);
            sy += __shfl_xor(sy, o);
            sz += __shfl_xor(sz, o);
            sq += __shfl_xor(sq, o);
        }
        if (lane == 0) {
            s_mn[wid][0] = mnx; s_mn[wid][1] = mny; s_mn[wid][2] = mnz;
            s_mx[wid][0] = mxx; s_mx[wid][1] = mxy; s_mx[wid][2] = mxz;
            s_sx[wid] = sx; s_sy[wid] = sy; s_sz[wid] = sz; s_sq[wid] = sq;
        }
        __syncthreads();
        if (tid == 0) {
            float a0 = s_mn[0][0], a1 = s_mn[0][1], a2 = s_mn[0][2];
            float b0 = s_mx[0][0], b1 = s_mx[0][1], b2 = s_mx[0][2];
            double tx = s_sx[0], ty = s_sy[0], tz = s_sz[0], tq = s_sq[0];
            for (int w = 1; w < 4; ++w) {
                a0 = fminf(a0, s_mn[w][0]); a1 = fminf(a1, s_mn[w][1]); a2 = fminf(a2, s_mn[w][2]);
                b0 = fmaxf(b0, s_mx[w][0]); b1 = fmaxf(b1, s_mx[w][1]); b2 = fmaxf(b2, s_mx[w][2]);
                tx += s_sx[w]; ty += s_sy[w]; tz += s_sz[w]; tq += s_sq[w];
            }
            float cx = 0.5f * (a0 + b0), cy = 0.5f * (a1 + b1), cz = 0.5f * (a2 + b2);
            g_nc4[n] = make_float4(cx, cy, cz, 0.5f * fmaxf(fmaxf(b0 - a0, b1 - a1), b2 - a2));
            const float fc = (float)cnt;
            g_nm4[n] = make_float4((float)tx / fc, (float)ty / fc, (float)tz / fc, (float)tq);
            s_cc[0] = cx; s_cc[1] = cy; s_cc[2] = cz;
            if (cnt <= LEAF_SZ) { g_nmeta[n] = make_int4(st, en, 0, 0); s_info = -1; }
            else s_info = 0;
        }
        __syncthreads();
        if (s_info < 0) {
            if (tid == 0) { __threadfence(); atomicAdd(&g_finished, 1); }
            continue;
        }
        const float cx = s_cc[0], cy = s_cc[1], cz = s_cc[2];

        // pass 2: octant counts
        int c8[8] = {0,0,0,0,0,0,0,0};
        for (int j = st + tid; j < en; j += 256) {
            float4 p = g_p4[j];
            int oct = (p.x >= cx ? 1 : 0) | (p.y >= cy ? 2 : 0) | (p.z >= cz ? 4 : 0);
            c8[oct]++;
        }
        #pragma unroll
        for (int k = 0; k < 8; ++k)
            for (int o = 1; o < 64; o <<= 1)
                c8[k] += __shfl_xor(c8[k], o);
        if (lane == 0)
            #pragma unroll
            for (int k = 0; k < 8; ++k) s_c8[wid][k] = c8[k];
        __syncthreads();
        if (tid == 0) {
            int tot[8], nonempty = 0;
            #pragma unroll
            for (int k = 0; k < 8; ++k) {
                tot[k] = s_c8[0][k] + s_c8[1][k] + s_c8[2][k] + s_c8[3][k];
                nonempty += (tot[k] > 0) ? 1 : 0;
            }
            if (nonempty <= 1) { g_nmeta[n] = make_int4(st, en, 0, 0); s_info = -1; }
            else {
                int base = atomicAdd(&g_ncount, nonempty);  // allocate before finishing
                int acc = st, ci = base;
                #pragma unroll
                for (int k = 0; k < 8; ++k) {
                    s_cur[k] = acc;
                    if (tot[k] > 0) { g_nstart[ci] = acc; g_nend[ci] = acc + tot[k]; ++ci; }
                    acc += tot[k];
                }
                g_nmeta[n] = make_int4(st, en, base, nonempty);
                s_base = base; s_num = nonempty; s_info = 1;
            }
        }
        __syncthreads();
        if (s_info < 0) {
            if (tid == 0) { __threadfence(); atomicAdd(&g_finished, 1); }
            continue;
        }

        // pass 3: scatter into child order
        for (int j = st + tid; j < en; j += 256) {
            float4 p = g_p4[j];
            int id = g_perm[j];
            int oct = (p.x >= cx ? 1 : 0) | (p.y >= cy ? 2 : 0) | (p.z >= cz ? 4 : 0);
            int pdst = atomicAdd(&s_cur[oct], 1);
            g_ptmp[pdst] = id; g_t4[pdst] = p;
        }
        __syncthreads();
        for (int j = st + tid; j < en; j += 256) {
            g_perm[j] = g_ptmp[j];
            g_p4[j]   = g_t4[j];
        }
        __syncthreads();
        if (tid == 0) {
            __threadfence();                        // release scattered data
            for (int c = 0; c < s_num; ++c) atomicExch(&g_ready[s_base + c], 1);
            atomicAdd(&g_finished, 1);
        }
    }
}

// ---------------------------------------------------------------------------
// One wave per target. Per batch: lanes classify nodes (monopole inline),
// leaf ranges prefix-summed into a flat LDS pair list, drained by all lanes.
// ---------------------------------------------------------------------------
__global__ __launch_bounds__(256)
void traverse_kernel(const int* __restrict__ batch,
                     const float* __restrict__ p_scr, const float* __restrict__ p_soft,
                     float* __restrict__ out, int N)
{
    __shared__ int s_q[4][NQ];
    __shared__ int s_pj[4][PCAP];
    __shared__ int s_qt[4];
    const int wid  = threadIdx.x >> 6;
    const int lane = threadIdx.x & 63;
    const int slot = blockIdx.x * 4 + wid;
    if (slot >= N) return;                 // wave-uniform; no __syncthreads used
    const int t = g_perm[slot];

    const float scr   = p_scr[0];
    const float soft  = p_soft[0];
    const float soft2 = soft * soft;
    const float cexp  = -scr * 1.4426950408889634f;  // exp(-scr*r) = exp2(cexp*r)
    const float4 tp = g_p4[slot];
    const float tx = tp.x, ty = tp.y, tz = tp.z;
    const int inv_t = slot;

    volatile int* q  = s_q[wid];
    volatile int* pj = s_pj[wid];
    if (lane == 0) { q[0] = g_root[batch[t]]; s_qt[wid] = 1; }
    __builtin_amdgcn_wave_barrier();

    float phi = 0.f;
    int qh = 0;
    while (true) {
        __builtin_amdgcn_wave_barrier();
        int qt = ((volatile int*)s_qt)[wid];
        if (qh >= qt) break;
        int take = qt - qh; if (take > 64) take = 64;
        int node = (lane < take) ? q[(qh + lane) & (NQ - 1)] : -1;
        qh += take;

        int leaf_st = 0, leaf_cnt = 0;
        if (node >= 0) {
            const int4 meta = g_nmeta[node];
            if (meta.w == 0) {
                leaf_st = meta.x; leaf_cnt = meta.y - meta.x;
            } else {
                float4 c4 = g_nc4[node];
                float dx = tx - c4.x, dy = ty - c4.y, dz = tz - c4.z;
                float dist = sqrtf(dx*dx + dy*dy + dz*dz + soft2);
                float diam = fmaxf(2.0f * c4.w, 1e-9f);
                bool inside = (inv_t >= meta.x) && (inv_t < meta.y);
                if (!inside && diam < 0.5f * dist) {
                    float4 m4 = g_nm4[node];
                    float ax = tx - m4.x, ay = ty - m4.y, az = tz - m4.z;
                    float s = ax*ax + ay*ay + az*az + soft2;
                    float rinv = rsqrtf(s);
                    phi += m4.w * exp2f(cexp * (s * rinv)) * rinv;
                } else {
                    int p = atomicAdd(&s_qt[wid], meta.w);
                    for (int c = 0; c < meta.w; ++c) q[(p + c) & (NQ - 1)] = meta.z + c;
                }
            }
        }

        // wave prefix-sum of (leaf size minus self) -> flat pair list
        bool hasself = (inv_t >= leaf_st) && (inv_t < leaf_st + leaf_cnt);
        int cnt_adj = leaf_cnt - (hasself ? 1 : 0);
        int x = cnt_adj;
        #pragma unroll
        for (int o = 1; o < 64; o <<= 1) { int y = __shfl_up(x, o); if (lane >= o) x += y; }
        int total = __shfl(x, 63);
        int off = x - cnt_adj;

        if (total > 0) {
            if (total <= PCAP) {
                int w = off;
                for (int k = 0; k < leaf_cnt; ++k) {
                    int j = leaf_st + k;
                    if (j != inv_t) pj[w++] = j;
                }
                __builtin_amdgcn_wave_barrier();
                for (int p = lane; p < total; p += 64) {
                    int j = pj[p];
                    float4 pp = g_p4[j];
                    float dx = tx - pp.x, dy = ty - pp.y, dz = tz - pp.z;
                    float s = dx*dx + dy*dy + dz*dz + soft2;
                    float rinv = rsqrtf(s);
                    phi += pp.w * exp2f(cexp * (s * rinv)) * rinv;
                }
                __builtin_amdgcn_wave_barrier();
            } else {
                // pathological huge-leaf fallback: serial per lane (never in practice)
                for (int k = 0; k < leaf_cnt; ++k) {
                    int j = leaf_st + k;
                    if (j == inv_t) continue;
                    float4 pp = g_p4[j];
                    float dx = tx - pp.x, dy = ty - pp.y, dz = tz - pp.z;
                    float s = dx*dx + dy*dy + dz*dz + soft2;
                    float rinv = rsqrtf(s);
                    phi += pp.w * exp2f(cexp * (s * rinv)) * rinv;
                }
            }
        }
    }

    #pragma unroll
    for (int o = 1; o < 64; o <<= 1) phi += __shfl_xor(phi, o);
    if (lane == 0) out[t] = 0.5f * (tp.w * phi);
}

extern "C" void kernel_launch(void* const* d_in, const int* in_sizes, int n_in,
                              void* d_out, int out_size, void* d_ws, size_t ws_size,
                              hipStream_t stream) {
    const float* pos    = (const float*)d_in[0];
    const int*   batch  = (const int*)  d_in[1];
    const float* source = (const float*)d_in[3];
    const float* p_scr  = (const float*)d_in[4];
    const float* p_soft = (const float*)d_in[5];

    const int N        = in_sizes[0] / 3;
    const int n_graphs = in_sizes[2] / 9;

    initA_kernel<<<(MAXNODES + 255) / 256, 256, 0, stream>>>(pos, source, N);
    initB_kernel<<<1, 256, 0, stream>>>(batch, N, n_graphs);
    build_kernel<<<BGRID, 256, 0, stream>>>();

    const int blocks = (N + 3) / 4;  // 4 waves (targets) per 256-thread block
    traverse_kernel<<<blocks, 256, 0, stream>>>(batch, p_scr, p_soft, (float*)d_out, N);
}